// Round 12
// baseline (148.076 us; speedup 1.0000x reference)
//
#include <hip/hip_runtime.h>

// STGraphConstructor: adj[b] = tanh(relu(A_b A_b^T) + I), A_b = [5096 x 64] fp32.
// R12: persistent dbuf pipeline with stores never drained in-loop.
//  - R9 failed because __syncthreads => s_waitcnt vmcnt(0) drained each tile's
//    64KB of stores serially. Here: raw s_barrier + manual lgkmcnt(0) only.
//  - Reg-staged col panel (load->reg early, ds_write late): compiler emits a
//    COUNTED vmcnt for the reg dependency, leaving the 16 stores in flight
//    across the barrier (AITER pattern: vmcnt never 0 in main loop).
//  - Fast path (bi,bj<39): exactly 16 unconditional float4 stores (tight count).
//    Edge tiles: guarded slow path (uniform per-tile branch, ~5% of iters).
//  - A-frags in registers per band; 512 blocks (2/CU); XCD-pinned bj-fastest
//    runs; all proven numerics (hi/lo x3 MFMA, swapped operands, XOR swizzle,
//    exp2-tanh) unchanged.

#define NSP 5000
#define NTM 96
#define MM  5096
#define DD  64
#define BT  128
#define NTILE 40

typedef __attribute__((ext_vector_type(8))) short short8;
typedef __attribute__((ext_vector_type(8))) unsigned short ushort8;
typedef __attribute__((ext_vector_type(4))) float f32x4;

__device__ __forceinline__ unsigned short bf16_rn(float x) {
  unsigned u = __float_as_uint(x);
  u += 0x7FFFu + ((u >> 16) & 1u);
  return (unsigned short)(u >> 16);
}
__device__ __forceinline__ float bf16_f32(unsigned short s) {
  return __uint_as_float(((unsigned)s) << 16);
}

// ---- prep: convert concat(sp,tm) [B][MM][DD] fp32 -> hi/lo bf16 panels ----
__global__ __launch_bounds__(256) void stg_prep_kernel(
    const float* __restrict__ sp, const float* __restrict__ tm,
    unsigned short* __restrict__ wsh, unsigned short* __restrict__ wsl) {
  const int tid = blockIdx.x * 256 + threadIdx.x;
  const int flat = tid * 8;
  const int b = flat / (MM * DD);
  const int rem = flat - b * (MM * DD);
  const int m = rem / DD;
  const int d = rem - m * DD;
  const float* src = (m < NSP)
      ? sp + ((size_t)b * NSP + m) * DD + d
      : tm + ((size_t)b * NTM + (m - NSP)) * DD + d;
  const float4* s4 = reinterpret_cast<const float4*>(src);
  float f[8];
  {
    float4 v0 = s4[0], v1 = s4[1];
    f[0]=v0.x; f[1]=v0.y; f[2]=v0.z; f[3]=v0.w;
    f[4]=v1.x; f[5]=v1.y; f[6]=v1.z; f[7]=v1.w;
  }
  ushort8 H, L;
  #pragma unroll
  for (int i = 0; i < 8; ++i) {
    const unsigned short hi = bf16_rn(f[i]);
    H[i] = hi;
    L[i] = bf16_rn(f[i] - bf16_f32(hi));
  }
  *reinterpret_cast<ushort8*>(wsh + flat) = H;
  *reinterpret_cast<ushort8*>(wsl + flat) = L;
}

// ---- main: persistent band-sweep, dbuf col panel, raw barriers ----
__global__ __launch_bounds__(256, 2) void stg_adj_kernel(
    const unsigned short* __restrict__ wsh,
    const unsigned short* __restrict__ wsl,
    float* __restrict__ out) {
  __shared__ unsigned char lds[2][32768];   // per buf: 16KB hi + 16KB lo

  // XCD pinning: x = wid%8 -> XCD; batch b owns residues {2b,2b+1}.
  const int wid = blockIdx.x;
  const int x = wid & 7;
  const int b = x >> 1;
  const int k = ((wid >> 3) << 1) + (x & 1);   // 0..127 within batch
  int tt0, len;
  if (k < 64) { tt0 = k * 13; len = 13; }
  else        { tt0 = 832 + (k - 64) * 12; len = 12; }

  const int t = threadIdx.x;
  const int lane = t & 63;
  const int wave = t >> 6;
  const int wr = (wave >> 1) << 6;
  const int wc = (wave & 1) << 6;
  const int lr = lane & 15;
  const int lg = lane >> 4;

  const size_t pb = (size_t)b * MM * DD;
  const unsigned short* Xh = wsh + pb;
  const unsigned short* Xl = wsl + pb;
  const size_t cbase = (size_t)b * MM * MM;

  // staging geometry: 4 granules per component per thread
  int srow[4], sg[4];
  #pragma unroll
  for (int kk = 0; kk < 4; ++kk) {
    const int G = t + kk * 256;
    srow[kk] = G >> 3;
    sg[kk] = G & 7;
  }

  // ---- prologue: stage tile tt0's col panel into buf 0 ----
  {
    const int bj0 = tt0 - (tt0 / NTILE) * NTILE;
    #pragma unroll
    for (int kk = 0; kk < 4; ++kk) {
      int grow = bj0 * BT + srow[kk]; grow = grow < MM ? grow : MM - 1;
      const ushort8 vh = *reinterpret_cast<const ushort8*>(Xh + (size_t)grow * DD + sg[kk] * 8);
      const ushort8 vl = *reinterpret_cast<const ushort8*>(Xl + (size_t)grow * DD + sg[kk] * 8);
      const unsigned db = (unsigned)srow[kk] * 128u + ((unsigned)(sg[kk] ^ (srow[kk] & 7)) << 4);
      *reinterpret_cast<ushort8*>(lds[0] + db) = vh;
      *reinterpret_cast<ushort8*>(lds[0] + 16384 + db) = vl;
    }
  }
  asm volatile("s_waitcnt lgkmcnt(0)" ::: "memory");
  __builtin_amdgcn_sched_barrier(0);
  __builtin_amdgcn_s_barrier();
  __builtin_amdgcn_sched_barrier(0);

  int cur = 0;
  int cur_bi = -1;
  short8 ah[4][2], al[4][2];

  for (int i = 0; i < len; ++i) {
    const int tt = tt0 + i;
    const int bi = tt / NTILE;
    const int bj = tt - bi * NTILE;

    // A-frag reload on band change (<=2x per block)
    if (bi != cur_bi) {
      cur_bi = bi;
      #pragma unroll
      for (int m = 0; m < 4; ++m) {
        int ra = bi * BT + wr + m * 16 + lr; ra = ra < MM ? ra : MM - 1;
        const unsigned short* ph = Xh + (size_t)ra * DD;
        const unsigned short* pl = Xl + (size_t)ra * DD;
        #pragma unroll
        for (int ks = 0; ks < 2; ++ks) {
          ah[m][ks] = *reinterpret_cast<const short8*>(ph + (lg + ks * 4) * 8);
          al[m][ks] = *reinterpret_cast<const short8*>(pl + (lg + ks * 4) * 8);
        }
      }
    }

    // [1] issue next tile's panel loads (regs) — latency hides under compute
    ushort8 nreg[8];
    const bool have_next = (i + 1 < len);
    if (have_next) {
      const int tn = tt + 1;
      const int bjn = tn - (tn / NTILE) * NTILE;
      #pragma unroll
      for (int kk = 0; kk < 4; ++kk) {
        int grow = bjn * BT + srow[kk]; grow = grow < MM ? grow : MM - 1;
        nreg[kk]     = *reinterpret_cast<const ushort8*>(Xh + (size_t)grow * DD + sg[kk] * 8);
        nreg[kk + 4] = *reinterpret_cast<const ushort8*>(Xl + (size_t)grow * DD + sg[kk] * 8);
      }
    }

    // [2] compute from lds[cur]
    f32x4 acc[4][4];
    #pragma unroll
    for (int m = 0; m < 4; ++m)
      #pragma unroll
      for (int n = 0; n < 4; ++n)
        acc[m][n] = (f32x4){0.f, 0.f, 0.f, 0.f};

    #pragma unroll
    for (int ks = 0; ks < 2; ++ks) {
      short8 ch[4], cl[4];
      #pragma unroll
      for (int n = 0; n < 4; ++n) {
        const int rc = wc + n * 16 + lr;
        const unsigned gcb = (unsigned)rc * 128u + ((unsigned)((lg + ks * 4) ^ (rc & 7)) << 4);
        ch[n] = *reinterpret_cast<short8*>(lds[cur] + gcb);
        cl[n] = *reinterpret_cast<short8*>(lds[cur] + 16384 + gcb);
      }
      #pragma unroll
      for (int m = 0; m < 4; ++m) {
        #pragma unroll
        for (int n = 0; n < 4; ++n) {
          acc[m][n] = __builtin_amdgcn_mfma_f32_16x16x32_bf16(ch[n], ah[m][ks], acc[m][n], 0, 0, 0);
          acc[m][n] = __builtin_amdgcn_mfma_f32_16x16x32_bf16(ch[n], al[m][ks], acc[m][n], 0, 0, 0);
          acc[m][n] = __builtin_amdgcn_mfma_f32_16x16x32_bf16(cl[n], ah[m][ks], acc[m][n], 0, 0, 0);
        }
      }
    }

    // [3] epilogue in place, then stores (never waited on)
    const int gr0 = bi * BT + wr;
    const int gc0 = bj * BT + wc;
    #pragma unroll
    for (int m = 0; m < 4; ++m)
      #pragma unroll
      for (int n = 0; n < 4; ++n)
        #pragma unroll
        for (int q = 0; q < 4; ++q)
          acc[m][n][q] = fmaxf(acc[m][n][q], 0.f);
    if (bi == bj) {
      #pragma unroll
      for (int m = 0; m < 4; ++m)
        #pragma unroll
        for (int n = 0; n < 4; ++n)
          #pragma unroll
          for (int q = 0; q < 4; ++q)
            if ((gr0 + m * 16 + lr) == (gc0 + n * 16 + lg * 4 + q)) acc[m][n][q] += 1.f;
    }
    #pragma unroll
    for (int m = 0; m < 4; ++m)
      #pragma unroll
      for (int n = 0; n < 4; ++n)
        #pragma unroll
        for (int q = 0; q < 4; ++q) {
          const float e = __builtin_amdgcn_exp2f(acc[m][n][q] * 2.8853900817779268f);
          acc[m][n][q] = 1.f - 2.f * __builtin_amdgcn_rcpf(e + 1.f);
        }

    if (bi < 39 && bj < 39) {
      // fast path: exactly 16 unconditional float4 stores
      #pragma unroll
      for (int m = 0; m < 4; ++m) {
        float* rowp = out + cbase + (size_t)(gr0 + m * 16 + lr) * MM;
        #pragma unroll
        for (int n = 0; n < 4; ++n)
          *reinterpret_cast<f32x4*>(rowp + gc0 + n * 16 + lg * 4) = acc[m][n];
      }
    } else {
      #pragma unroll
      for (int m = 0; m < 4; ++m) {
        const int gr = gr0 + m * 16 + lr;
        if (gr < MM) {
          float* rowp = out + cbase + (size_t)gr * MM;
          #pragma unroll
          for (int n = 0; n < 4; ++n) {
            const int gc = gc0 + n * 16 + lg * 4;
            if (gc < MM)
              *reinterpret_cast<f32x4*>(rowp + gc) = acc[m][n];
          }
        }
      }
    }

    // [4] write staged regs to other buffer; barrier WITHOUT vmcnt drain
    if (have_next) {
      unsigned char* dstb = lds[cur ^ 1];
      #pragma unroll
      for (int kk = 0; kk < 4; ++kk) {
        const unsigned db = (unsigned)srow[kk] * 128u + ((unsigned)(sg[kk] ^ (srow[kk] & 7)) << 4);
        *reinterpret_cast<ushort8*>(dstb + db) = nreg[kk];
        *reinterpret_cast<ushort8*>(dstb + 16384 + db) = nreg[kk + 4];
      }
      asm volatile("s_waitcnt lgkmcnt(0)" ::: "memory");
      __builtin_amdgcn_sched_barrier(0);
      __builtin_amdgcn_s_barrier();
      __builtin_amdgcn_sched_barrier(0);
    }
    cur ^= 1;
  }
}

extern "C" void kernel_launch(void* const* d_in, const int* in_sizes, int n_in,
                              void* d_out, int out_size, void* d_ws, size_t ws_size,
                              hipStream_t stream) {
  const float* sp = (const float*)d_in[0];
  const float* tm = (const float*)d_in[1];
  float* out = (float*)d_out;
  const int B = in_sizes[0] / (NSP * DD);   // = 4
  unsigned short* wsh = (unsigned short*)d_ws;
  unsigned short* wsl = wsh + (size_t)B * MM * DD;

  const int prep_threads = B * MM * DD / 8;
  stg_prep_kernel<<<dim3(prep_threads / 256), dim3(256), 0, stream>>>(sp, tm, wsh, wsl);

  stg_adj_kernel<<<dim3(512), dim3(256), 0, stream>>>(wsh, wsl, out);
}

// Round 13
// 109.648 us; speedup vs baseline: 1.3505x; 1.3505x over previous
//
#include <hip/hip_runtime.h>

// STGraphConstructor: adj[b] = tanh(relu(A_b A_b^T) + I), A_b = [5096 x 64] fp32.
// R13: R8 structure at 64x64 tiles => 5 blocks/CU for store-phase coverage.
//  - R8 model: time ~= serial sum (stores 64us + epilogue 17 + staging 12 + mfma 3).
//    Store duty ~30%/block; coverage = 1-(1-0.3)^N. N=2 (R8) -> 51% -> 3.9 TB/s.
//    N=5 -> 83% -> ~5.4 TB/s. Persistence (R9/R12) and store-pattern variants
//    (R2,R5,R6,R7,R11) all failed; one-shot turnover + more residency is the lever.
//  - 32KB LDS (2 panels x (8KB hi + 8KB lo)), __launch_bounds__(256,5).
//  - All proven pieces verbatim: prep kernel, coalesced XOR-swizzled staging,
//    hi/lo x3 MFMA, swapped operands, exp2-tanh, float4 bursts, no post-store sync.

#define NSP 5000
#define NTM 96
#define MM  5096
#define DD  64
#define TB  64
#define NT  80     // ceil(5096/64)

typedef __attribute__((ext_vector_type(8))) short short8;
typedef __attribute__((ext_vector_type(8))) unsigned short ushort8;
typedef __attribute__((ext_vector_type(4))) float f32x4;

__device__ __forceinline__ unsigned short bf16_rn(float x) {
  unsigned u = __float_as_uint(x);
  u += 0x7FFFu + ((u >> 16) & 1u);
  return (unsigned short)(u >> 16);
}
__device__ __forceinline__ float bf16_f32(unsigned short s) {
  return __uint_as_float(((unsigned)s) << 16);
}

// ---- prep: convert concat(sp,tm) [B][MM][DD] fp32 -> hi/lo bf16 panels ----
__global__ __launch_bounds__(256) void stg_prep_kernel(
    const float* __restrict__ sp, const float* __restrict__ tm,
    unsigned short* __restrict__ wsh, unsigned short* __restrict__ wsl) {
  const int tid = blockIdx.x * 256 + threadIdx.x;
  const int flat = tid * 8;
  const int b = flat / (MM * DD);
  const int rem = flat - b * (MM * DD);
  const int m = rem / DD;
  const int d = rem - m * DD;
  const float* src = (m < NSP)
      ? sp + ((size_t)b * NSP + m) * DD + d
      : tm + ((size_t)b * NTM + (m - NSP)) * DD + d;
  const float4* s4 = reinterpret_cast<const float4*>(src);
  float f[8];
  {
    float4 v0 = s4[0], v1 = s4[1];
    f[0]=v0.x; f[1]=v0.y; f[2]=v0.z; f[3]=v0.w;
    f[4]=v1.x; f[5]=v1.y; f[6]=v1.z; f[7]=v1.w;
  }
  ushort8 H, L;
  #pragma unroll
  for (int i = 0; i < 8; ++i) {
    const unsigned short hi = bf16_rn(f[i]);
    H[i] = hi;
    L[i] = bf16_rn(f[i] - bf16_f32(hi));
  }
  *reinterpret_cast<ushort8*>(wsh + flat) = H;
  *reinterpret_cast<ushort8*>(wsl + flat) = L;
}

// ---- main: 64x64 tile, 32KB LDS, 5 blocks/CU ----
__global__ __launch_bounds__(256, 5) void stg_adj_kernel(
    const unsigned short* __restrict__ wsh,
    const unsigned short* __restrict__ wsl,
    float* __restrict__ out) {
  __shared__ unsigned char lds[32768];   // RH(8K), RL(8K), CH(8K), CL(8K)
  const int bi = blockIdx.x;
  const int bj = blockIdx.y;
  const int b  = blockIdx.z;
  const int t  = threadIdx.x;

  const size_t pb = (size_t)b * MM * DD;
  const unsigned short* Xh = wsh + pb;
  const unsigned short* Xl = wsl + pb;

  // ---- stage 4 x 8KB panels: 2 coalesced 16B granules/thread/comp ----
  #pragma unroll
  for (int comp = 0; comp < 4; ++comp) {
    const int tbase = (comp < 2 ? bi : bj) * TB;
    const unsigned short* src = (comp & 1) ? Xl : Xh;
    unsigned char* dst = lds + comp * 8192;
    #pragma unroll
    for (int k = 0; k < 2; ++k) {
      const int G = t + k * 256;          // granule 0..511
      const int row = G >> 3;             // 0..63
      const int g = G & 7;                // 16B granule within row
      int grow = tbase + row; grow = grow < MM ? grow : MM - 1;
      const ushort8 v = *reinterpret_cast<const ushort8*>(src + (size_t)grow * DD + g * 8);
      *reinterpret_cast<ushort8*>(dst + row * 128 + ((g ^ (row & 7)) << 4)) = v;
    }
  }
  __syncthreads();

  // ---- compute: wave w owns rows w*16..w*16+15, all 64 cols ----
  const int lane = t & 63;
  const int wave = t >> 6;
  const int lr = lane & 15;
  const int lg = lane >> 4;

  f32x4 acc[4];
  #pragma unroll
  for (int n = 0; n < 4; ++n) acc[n] = (f32x4){0.f, 0.f, 0.f, 0.f};

  // A-frags: wave's 16 rows from row panel
  const int ra = wave * 16 + lr;
  short8 ahf[2], alf[2];
  #pragma unroll
  for (int ks = 0; ks < 2; ++ks) {
    const unsigned ga = (unsigned)ra * 128u + ((unsigned)((lg + ks * 4) ^ (ra & 7)) << 4);
    ahf[ks] = *reinterpret_cast<short8*>(lds + ga);
    alf[ks] = *reinterpret_cast<short8*>(lds + 8192 + ga);
  }

  #pragma unroll
  for (int ks = 0; ks < 2; ++ks) {
    short8 ch[4], cl[4];
    #pragma unroll
    for (int n = 0; n < 4; ++n) {
      const int rc = n * 16 + lr;
      const unsigned gcb = (unsigned)rc * 128u + ((unsigned)((lg + ks * 4) ^ (rc & 7)) << 4);
      ch[n] = *reinterpret_cast<short8*>(lds + 16384 + gcb);
      cl[n] = *reinterpret_cast<short8*>(lds + 24576 + gcb);
    }
    // swapped operands: lane holds row bi*64+wave*16+lr, cols bj*64+n*16+lg*4+q
    #pragma unroll
    for (int n = 0; n < 4; ++n) {
      acc[n] = __builtin_amdgcn_mfma_f32_16x16x32_bf16(ch[n], ahf[ks], acc[n], 0, 0, 0);
      acc[n] = __builtin_amdgcn_mfma_f32_16x16x32_bf16(ch[n], alf[ks], acc[n], 0, 0, 0);
      acc[n] = __builtin_amdgcn_mfma_f32_16x16x32_bf16(cl[n], ahf[ks], acc[n], 0, 0, 0);
    }
  }

  // ---- epilogue: tanh(relu(x)[+eye]), float4 burst stores, nothing after ----
  const int gr = bi * TB + wave * 16 + lr;
  const int gc0 = bj * TB;
  if (gr < MM) {
    float* rowp = out + (size_t)b * MM * MM + (size_t)gr * MM;
    #pragma unroll
    for (int n = 0; n < 4; ++n) {
      const int gc = gc0 + n * 16 + lg * 4;
      if (gc < MM) {   // gc, MM multiples of 4 => whole float4 in bounds
        f32x4 v;
        #pragma unroll
        for (int q = 0; q < 4; ++q) {
          float xv = fmaxf(acc[n][q], 0.f);
          if (bi == bj) xv += (gr == gc + q) ? 1.f : 0.f;
          const float e = __builtin_amdgcn_exp2f(xv * 2.8853900817779268f);
          v[q] = 1.f - 2.f * __builtin_amdgcn_rcpf(e + 1.f);
        }
        *reinterpret_cast<f32x4*>(rowp + gc) = v;
      }
    }
  }
}

extern "C" void kernel_launch(void* const* d_in, const int* in_sizes, int n_in,
                              void* d_out, int out_size, void* d_ws, size_t ws_size,
                              hipStream_t stream) {
  const float* sp = (const float*)d_in[0];
  const float* tm = (const float*)d_in[1];
  float* out = (float*)d_out;
  const int B = in_sizes[0] / (NSP * DD);   // = 4
  unsigned short* wsh = (unsigned short*)d_ws;
  unsigned short* wsl = wsh + (size_t)B * MM * DD;

  const int prep_threads = B * MM * DD / 8;
  stg_prep_kernel<<<dim3(prep_threads / 256), dim3(256), 0, stream>>>(sp, tm, wsh, wsl);

  dim3 grid(NT, NT, B);
  stg_adj_kernel<<<grid, dim3(256), 0, stream>>>(wsh, wsl, out);
}